// Round 5
// baseline (692.718 us; speedup 1.0000x reference)
//
#include <hip/hip_runtime.h>

// Paged attention decode, GQA: B=32, H=32, KVH=8 (G=4), D=128, pages of 16.
// R5: (a) diagnostic bw_probe streaming the identical paged access pattern at
// full occupancy, 6 reps, so its rocprof counters appear in the top-5 table;
// (b) partial kernel with quarter-page (4-token) register ping-pong (fewer
// VGPRs -> 4 blocks/CU), fully static unrolled chunk loop, prefetched page
// indices. One block per (b, part); block serves all 8 kv heads so each
// physical page is read once, contiguously.

constexpr int Dh   = 128;
constexpr int Gq   = 4;
constexpr int KVH  = 8;
constexpr int Hq   = 32;
constexpr int Bb   = 32;
constexpr int MB   = 256;
constexpr int PAGE = 16;
constexpr float SCALE = 0.08838834764831845f;

constexpr int NPARTS      = 64;
constexpr int PART_TOKENS = 64;                  // 4 pages per part
constexpr int PG_FLOATS   = PAGE * KVH * Dh;     // 16384 floats = 64 KB
constexpr int ROW_FLOATS  = KVH * Dh;            // 1024 floats per token

// per-(b,part) workspace floats: acc[32 heads][128] + m[32] + l[32]
constexpr int PART_STRIDE = Hq * Dh + 2 * Hq;    // 4160

struct QuadR { float4 k[4], v[4]; };             // 4 tokens x 4 floats of K and V

__global__ __launch_bounds__(256, 4)
void attn_partial(const float* __restrict__ q,
                  const float* __restrict__ kc,
                  const float* __restrict__ vc,
                  const int*   __restrict__ bt,
                  const int*   __restrict__ cl,
                  float*       __restrict__ ws)
{
    const int part = blockIdx.x & (NPARTS - 1);
    const int b    = blockIdx.x >> 6;

    const int ctx    = cl[b];
    const int pstart = part * PART_TOKENS;
    if (pstart >= ctx) return;
    const int n  = min(PART_TOKENS, ctx - pstart);
    const int TC = (n + 3) >> 2;                 // 4-token chunks, 1..16

    const int t      = threadIdx.x;              // 0..255
    const int kvh    = t >> 5;
    const int lane32 = t & 31;
    const int doff   = lane32 * 4;
    const int t4     = t * 4;                    // this thread's float offset in a row

    // prefetch the 4 page indices for this part (16B aligned)
    const int4 pg = *(const int4*)(bt + b * MB + (pstart >> 4));

    // Q fragments, pre-scaled
    float4 qv[Gq];
    {
        const float* qbase = q + (size_t)(b * Hq + kvh * Gq) * Dh + doff;
        #pragma unroll
        for (int g = 0; g < Gq; ++g) {
            float4 x = *(const float4*)(qbase + g * Dh);
            qv[g] = make_float4(x.x * SCALE, x.y * SCALE, x.z * SCALE, x.w * SCALE);
        }
    }

    float4 acc[Gq];
    float  m_run[Gq], l_run[Gq];
    #pragma unroll
    for (int g = 0; g < Gq; ++g) {
        acc[g] = make_float4(0.f, 0.f, 0.f, 0.f);
        m_run[g] = -1e30f;
        l_run[g] = 0.f;
    }

    QuadR A, B;

#define LOADQ(H, c, phys)                                                      \
    {                                                                          \
        const size_t off = (size_t)(phys) * PG_FLOATS                          \
                         + ((c) & 3) * (4 * ROW_FLOATS) + t4;                  \
        const float* kp = kc + off;                                            \
        const float* vp = vc + off;                                            \
        H.k[0] = *(const float4*)(kp + 0 * ROW_FLOATS);                        \
        H.k[1] = *(const float4*)(kp + 1 * ROW_FLOATS);                        \
        H.k[2] = *(const float4*)(kp + 2 * ROW_FLOATS);                        \
        H.k[3] = *(const float4*)(kp + 3 * ROW_FLOATS);                        \
        H.v[0] = *(const float4*)(vp + 0 * ROW_FLOATS);                        \
        H.v[1] = *(const float4*)(vp + 1 * ROW_FLOATS);                        \
        H.v[2] = *(const float4*)(vp + 2 * ROW_FLOATS);                        \
        H.v[3] = *(const float4*)(vp + 3 * ROW_FLOATS);                        \
    }

#define COMPUTEQ(H, c)                                                         \
    {                                                                          \
        const int tb = (c) * 4;                                                \
        float s[4][Gq];                                                        \
        _Pragma("unroll")                                                      \
        for (int j = 0; j < 4; ++j) {                                          \
            const bool vj = (tb + j) < n;                                      \
            _Pragma("unroll")                                                  \
            for (int g = 0; g < Gq; ++g) {                                     \
                float d = H.k[j].x * qv[g].x + H.k[j].y * qv[g].y              \
                        + H.k[j].z * qv[g].z + H.k[j].w * qv[g].w;             \
                d += __shfl_xor(d, 1);                                         \
                d += __shfl_xor(d, 2);                                         \
                d += __shfl_xor(d, 4);                                         \
                d += __shfl_xor(d, 8);                                         \
                d += __shfl_xor(d, 16);                                        \
                s[j][g] = vj ? d : -1e30f;                                     \
            }                                                                  \
        }                                                                      \
        _Pragma("unroll")                                                      \
        for (int g = 0; g < Gq; ++g) {                                         \
            float tm = fmaxf(fmaxf(s[0][g], s[1][g]), fmaxf(s[2][g], s[3][g]));\
            const float mn    = fmaxf(m_run[g], tm);                           \
            const float alpha = __expf(m_run[g] - mn);                         \
            m_run[g] = mn;                                                     \
            float p0 = __expf(s[0][g] - mn);                                   \
            float p1 = __expf(s[1][g] - mn);                                   \
            float p2 = __expf(s[2][g] - mn);                                   \
            float p3 = __expf(s[3][g] - mn);                                   \
            l_run[g] = l_run[g] * alpha + (p0 + p1 + p2 + p3);                 \
            acc[g].x = fmaf(p3, H.v[3].x, fmaf(p2, H.v[2].x,                   \
                       fmaf(p1, H.v[1].x, fmaf(p0, H.v[0].x, acc[g].x * alpha))));\
            acc[g].y = fmaf(p3, H.v[3].y, fmaf(p2, H.v[2].y,                   \
                       fmaf(p1, H.v[1].y, fmaf(p0, H.v[0].y, acc[g].y * alpha))));\
            acc[g].z = fmaf(p3, H.v[3].z, fmaf(p2, H.v[2].z,                   \
                       fmaf(p1, H.v[1].z, fmaf(p0, H.v[0].z, acc[g].z * alpha))));\
            acc[g].w = fmaf(p3, H.v[3].w, fmaf(p2, H.v[2].w,                   \
                       fmaf(p1, H.v[1].w, fmaf(p0, H.v[0].w, acc[g].w * alpha))));\
        }                                                                      \
    }

#define STEPQ(c, CUR, NXT, PHYS_NXT)                                           \
    if ((c) + 1 < TC) LOADQ(NXT, (c) + 1, PHYS_NXT);                           \
    COMPUTEQ(CUR, (c));                                                        \
    if ((c) + 1 >= TC) goto done;

    LOADQ(A, 0, pg.x);
    STEPQ(0,  A, B, pg.x);
    STEPQ(1,  B, A, pg.x);
    STEPQ(2,  A, B, pg.x);
    STEPQ(3,  B, A, pg.y);
    STEPQ(4,  A, B, pg.y);
    STEPQ(5,  B, A, pg.y);
    STEPQ(6,  A, B, pg.y);
    STEPQ(7,  B, A, pg.z);
    STEPQ(8,  A, B, pg.z);
    STEPQ(9,  B, A, pg.z);
    STEPQ(10, A, B, pg.z);
    STEPQ(11, B, A, pg.w);
    STEPQ(12, A, B, pg.w);
    STEPQ(13, B, A, pg.w);
    STEPQ(14, A, B, pg.w);
    COMPUTEQ(B, 15);
done:;

    float* wp = ws + (size_t)(b * NPARTS + part) * PART_STRIDE;
    #pragma unroll
    for (int g = 0; g < Gq; ++g)
        *(float4*)(wp + (kvh * Gq + g) * Dh + doff) = acc[g];
    if (lane32 == 0) {
        #pragma unroll
        for (int g = 0; g < Gq; ++g) {
            wp[Hq * Dh + kvh * Gq + g]      = m_run[g];
            wp[Hq * Dh + Hq + kvh * Gq + g] = l_run[g];
        }
    }
#undef LOADQ
#undef COMPUTEQ
#undef STEPQ
}

__global__ __launch_bounds__(256, 4)
void attn_reduce(const float* __restrict__ ws,
                 const int*   __restrict__ cl,
                 float*       __restrict__ out)
{
    const int b       = blockIdx.x >> 2;
    const int quarter = blockIdx.x & 3;
    const int tid     = threadIdx.x;
    const int h       = quarter * 8 + (tid >> 5);
    const int doff    = (tid & 31) * 4;

    const int ctx = cl[b];
    const int np  = min(NPARTS, (ctx + PART_TOKENS - 1) / PART_TOKENS);

    const float* base = ws + (size_t)b * NPARTS * PART_STRIDE;

    float m = -1e30f;
    for (int p = 0; p < np; ++p)
        m = fmaxf(m, base[p * PART_STRIDE + Hq * Dh + h]);

    float L = 0.f;
    float ax = 0.f, ay = 0.f, az = 0.f, aw = 0.f;
    for (int p = 0; p < np; ++p) {
        const float* bp = base + p * PART_STRIDE;
        const float c = __expf(bp[Hq * Dh + h] - m);
        L += bp[Hq * Dh + Hq + h] * c;
        const float4 v = *(const float4*)(bp + h * Dh + doff);
        ax = fmaf(c, v.x, ax);
        ay = fmaf(c, v.y, ay);
        az = fmaf(c, v.z, az);
        aw = fmaf(c, v.w, aw);
    }
    const float inv = 1.f / L;
    float* op = out + (size_t)(b * Hq + h) * Dh + doff;
    *(float4*)op = make_float4(ax * inv, ay * inv, az * inv, aw * inv);
}

// Diagnostic: stream the identical paged access pattern (same pages, same
// masking) with no compute, full occupancy, 6 reps so this dispatch's
// counters appear in the rocprof top-5 table. Writes a checksum to a far
// region of ws (deterministic).
__global__ __launch_bounds__(256, 8)
void bw_probe(const float* __restrict__ kc,
              const float* __restrict__ vc,
              const int*   __restrict__ bt,
              const int*   __restrict__ cl,
              float*       __restrict__ sink)
{
    const int nblk = gridDim.x;
    float acc = 0.f;
    for (int rep = 0; rep < 6; ++rep) {
        for (int idx = blockIdx.x; idx < Bb * MB; idx += nblk) {
            const int b  = idx >> 8;             // MB = 256
            const int lp = idx & 255;
            if (lp * PAGE >= cl[b]) continue;
            const int phys = bt[b * MB + lp];
            const float* kp = kc + (size_t)phys * PG_FLOATS + threadIdx.x * 4;
            const float* vp = vc + (size_t)phys * PG_FLOATS + threadIdx.x * 4;
            #pragma unroll
            for (int j = 0; j < 16; ++j) {
                float4 a = *(const float4*)(kp + j * ROW_FLOATS);
                float4 c = *(const float4*)(vp + j * ROW_FLOATS);
                acc += a.x + a.y + a.z + a.w + c.x + c.y + c.z + c.w;
            }
        }
    }
    sink[blockIdx.x * 256 + threadIdx.x] = acc;
}

extern "C" void kernel_launch(void* const* d_in, const int* in_sizes, int n_in,
                              void* d_out, int out_size, void* d_ws, size_t ws_size,
                              hipStream_t stream) {
    const float* q  = (const float*)d_in[0];
    const float* kc = (const float*)d_in[1];
    const float* vc = (const float*)d_in[2];
    const int*   bt = (const int*)d_in[3];
    const int*   cl = (const int*)d_in[4];
    float* out = (float*)d_out;
    float* ws  = (float*)d_ws;

    attn_partial<<<dim3(Bb * NPARTS), dim3(256), 0, stream>>>(q, kc, vc, bt, cl, ws);
    attn_reduce<<<dim3(Bb * 4), dim3(256), 0, stream>>>(ws, cl, out);

    // diagnostic probe (remove once BW question is answered)
    float* sink = ws + ((size_t)1 << 25);        // 128 MB offset, clear of partials
    bw_probe<<<dim3(2048), dim3(256), 0, stream>>>(kc, vc, bt, cl, sink);
}